// Round 3
// baseline (265.172 us; speedup 1.0000x reference)
//
#include <hip/hip_runtime.h>
#include <cstdint>

#define SRC_LEN 2048
#define BSZ     64
#define CTX     512
#define ATT     256
#define NT      16          // K tiles = CTX/BK, BK=32
#define NCHUNK  16
#define LOG2E   1.4426950408889634f
#define BFRAG_HALF 262144   // bytes per (hi|lo) half of fragment-major B

typedef unsigned short u16;
typedef unsigned int   u32;
typedef unsigned char  u8;
typedef __attribute__((ext_vector_type(8))) short bf16x8;
typedef __attribute__((ext_vector_type(4))) float f32x4;

union U4BF8 { uint4 u; bf16x8 v; };

__device__ __forceinline__ u16 f2bf(float f) {
    u32 u = __float_as_uint(f);
    u32 r = (u + 0x7FFFu + ((u >> 16) & 1u)) >> 16;
    return (u16)r;
}
__device__ __forceinline__ float bf2f(u16 h) { return __uint_as_float((u32)h << 16); }
__device__ __forceinline__ u32 pack2(float a, float b) {
    return (u32)f2bf(a) | ((u32)f2bf(b) << 16);
}

__device__ __forceinline__ float fast_exp2(float x) {
#if __has_builtin(__builtin_amdgcn_exp2f)
    return __builtin_amdgcn_exp2f(x);
#else
    return exp2f(x);
#endif
}
__device__ __forceinline__ float fast_rcp(float x) {
#if __has_builtin(__builtin_amdgcn_rcpf)
    return __builtin_amdgcn_rcpf(x);
#else
    return 1.0f / x;
#endif
}
__device__ __forceinline__ float fast_tanh(float x) {
    float e = fast_exp2(x * (2.0f * LOG2E));
    return 1.0f - 2.0f * fast_rcp(e + 1.0f);
}

// ---------------------------------------------------------------------------
// Kernel 1: prep — decoder projection; W_enc hi/lo split written in
// FRAGMENT-MAJOR layout (h, t, wave, n, lane) for direct register loads.
// grid 64, 256 threads
// ---------------------------------------------------------------------------
__global__ __launch_bounds__(256) void prep_kernel(
    const float* __restrict__ dec_state, const float* __restrict__ W_dec,
    const float* __restrict__ W_enc, const u8* __restrict__ mask_bytes,
    float* __restrict__ decproj, u8* __restrict__ bfrag,
    int* __restrict__ flag)
{
    const int b = blockIdx.x, t = threadIdx.x;
    __shared__ float ds[CTX];
    for (int k = t; k < CTX; k += 256) ds[k] = dec_state[b * CTX + k];
    __syncthreads();

    // decproj[b][t] = dot(dec_state[b,:], W_dec[t,:])
    const float* wrow = W_dec + t * CTX;
    float acc = 0.f;
#pragma unroll 4
    for (int k = 0; k < CTX; k += 4) {
        float4 w4 = *reinterpret_cast<const float4*>(wrow + k);
        acc += w4.x * ds[k] + w4.y * ds[k + 1] + w4.z * ds[k + 2] + w4.w * ds[k + 3];
    }
    decproj[b * ATT + t] = acc;

    // one thread per (tile, wave, n, lane): 8 consecutive k of one W_enc row
    const int gid  = b * 256 + t;          // 0..16383
    const int lane = gid & 63;
    const int n    = (gid >> 6) & 3;
    const int w    = (gid >> 8) & 3;
    const int tt   = (gid >> 10) & 15;
    const int col  = w * 64 + n * 16 + (lane & 15);   // W_enc row = att col
    const int k0   = tt * 32 + (lane >> 4) * 8;
    const float* src = W_enc + col * CTX + k0;
    float4 f0 = reinterpret_cast<const float4*>(src)[0];
    float4 f1 = reinterpret_cast<const float4*>(src)[1];
    float fv[8] = {f0.x, f0.y, f0.z, f0.w, f1.x, f1.y, f1.z, f1.w};
    u32 hp[4], lp[4];
#pragma unroll
    for (int j = 0; j < 4; ++j) {
        u16 h0 = f2bf(fv[2 * j]), h1 = f2bf(fv[2 * j + 1]);
        u16 l0 = f2bf(fv[2 * j] - bf2f(h0));
        u16 l1 = f2bf(fv[2 * j + 1] - bf2f(h1));
        hp[j] = (u32)h0 | ((u32)h1 << 16);
        lp[j] = (u32)l0 | ((u32)l1 << 16);
    }
    const int dst = tt * 16384 + w * 4096 + n * 1024 + lane * 16;  // bytes
    uint4 uh = {hp[0], hp[1], hp[2], hp[3]};
    uint4 ul = {lp[0], lp[1], lp[2], lp[3]};
    *reinterpret_cast<uint4*>(bfrag + dst) = uh;
    *reinterpret_cast<uint4*>(bfrag + BFRAG_HALF + dst) = ul;

    // mask dtype probe (int32 0/1 has zero bytes at idx%4!=0)
    int bad = 0;
#pragma unroll
    for (int i = 0; i < 8; ++i) {
        int idx = gid * 8 + i;
        if ((idx & 3) != 0 && mask_bytes[idx] != 0) bad = 1;
    }
    if (bad) atomicOr(flag, 1);
}

// ---------------------------------------------------------------------------
// Kernel 2: score — barrier-free reg-staged MFMA GEMM + tanh/v-dot epilogue.
// Block = one s (64 rows = all b), 4 waves x 64 att-cols each.
// A fragments: direct global loads (ping-pong). B fragments: direct from
// fragment-major L2-hot buffer. NO LDS in the K-loop, no __syncthreads.
// grid 2048, 256 threads
// ---------------------------------------------------------------------------
__global__ __launch_bounds__(256, 2) void score_kernel(
    const float* __restrict__ hids, const u8* __restrict__ bfrag,
    const float* __restrict__ decproj, const float* __restrict__ b_enc,
    const float* __restrict__ vvec, const u8* __restrict__ maskB,
    const int* __restrict__ maskI, const int* __restrict__ flag,
    float* __restrict__ scoresT)
{
    __shared__ float spart[4][64];

    const int tid  = threadIdx.x;
    const int wave = tid >> 6, lane = tid & 63;
    const int ln15 = lane & 15, lg = lane >> 4;
    const int s    = blockIdx.x;

    f32x4 acc[4][4];
#pragma unroll
    for (int m = 0; m < 4; ++m)
#pragma unroll
        for (int n = 0; n < 4; ++n) acc[m][n] = (f32x4){0.f, 0.f, 0.f, 0.f};

    // per-lane A base per m-frag: row = s*64 + m*16 + ln15, k-sub = lg*8
    const float* ab[4];
#pragma unroll
    for (int m = 0; m < 4; ++m)
        ab[m] = hids + (size_t)(s * 64 + m * 16 + ln15) * CTX + lg * 8;

    const u8* bbH = bfrag + wave * 4096 + lane * 16;
    const u8* bbL = bbH + BFRAG_HALF;

    float4 aB[2][4][2];
    uint4  bhB[2][4], blB[2][4];

    auto LOADT = [&](int buf, int t) {
#pragma unroll
        for (int m = 0; m < 4; ++m) {
            aB[buf][m][0] = *reinterpret_cast<const float4*>(ab[m] + t * 32);
            aB[buf][m][1] = *reinterpret_cast<const float4*>(ab[m] + t * 32 + 4);
        }
#pragma unroll
        for (int n = 0; n < 4; ++n) {
            bhB[buf][n] = *reinterpret_cast<const uint4*>(bbH + t * 16384 + n * 1024);
            blB[buf][n] = *reinterpret_cast<const uint4*>(bbL + t * 16384 + n * 1024);
        }
    };

    LOADT(0, 0);
#pragma unroll
    for (int t = 0; t < NT; ++t) {
        const int cur = t & 1;
        if (t < NT - 1) LOADT(cur ^ 1, t + 1);

        bf16x8 abf[4];
#pragma unroll
        for (int m = 0; m < 4; ++m) {
            U4BF8 u;
            u.u.x = pack2(aB[cur][m][0].x, aB[cur][m][0].y);
            u.u.y = pack2(aB[cur][m][0].z, aB[cur][m][0].w);
            u.u.z = pack2(aB[cur][m][1].x, aB[cur][m][1].y);
            u.u.w = pack2(aB[cur][m][1].z, aB[cur][m][1].w);
            abf[m] = u.v;
        }
#pragma unroll
        for (int m = 0; m < 4; ++m) {
#pragma unroll
            for (int n = 0; n < 4; ++n) {
                U4BF8 bh, bl;
                bh.u = bhB[cur][n];
                bl.u = blB[cur][n];
                acc[m][n] = __builtin_amdgcn_mfma_f32_16x16x32_bf16(abf[m], bh.v, acc[m][n], 0, 0, 0);
                acc[m][n] = __builtin_amdgcn_mfma_f32_16x16x32_bf16(abf[m], bl.v, acc[m][n], 0, 0, 0);
            }
        }
    }

    // ---- epilogue: x = enc + b_enc + decproj; partial = sum tanh(x)*v ----
    float bE[4], vE[4];
#pragma unroll
    for (int n = 0; n < 4; ++n) {
        const int a = wave * 64 + n * 16 + ln15;
        bE[n] = b_enc[a];
        vE[n] = vvec[a];
    }
    const float* dpb = decproj + wave * 64 + ln15;
#pragma unroll
    for (int m = 0; m < 4; ++m) {
#pragma unroll
        for (int j = 0; j < 4; ++j) {
            const int rl = m * 16 + lg * 4 + j;     // = b index
            float partial = 0.f;
#pragma unroll
            for (int n = 0; n < 4; ++n) {
                float x = acc[m][n][j] + bE[n] + dpb[rl * ATT + n * 16];
                partial += fast_tanh(x) * vE[n];
            }
            partial += __shfl_xor(partial, 1);
            partial += __shfl_xor(partial, 2);
            partial += __shfl_xor(partial, 4);
            partial += __shfl_xor(partial, 8);
            if (ln15 == 0) spart[wave][rl] = partial;
        }
    }
    __syncthreads();

    if (tid < 64) {
        const int b = tid;
        float sc = spart[0][b] + spart[1][b] + spart[2][b] + spart[3][b];
        const int isByte = *flag;
        int mv;
        if (isByte) mv = (int)maskB[s * BSZ + b];
        else        mv = maskI[s * BSZ + b];
        scoresT[b * SRC_LEN + s] = (mv != 0) ? -1e30f : sc;
    }
}

// ---------------------------------------------------------------------------
// Kernel 3: softmax over s per batch column b. grid 64, 256 threads.
// ---------------------------------------------------------------------------
__global__ __launch_bounds__(256) void softmax_kernel(
    const float* __restrict__ scoresT, float* __restrict__ wT,
    float* __restrict__ outNorm)
{
    const int b = blockIdx.x, t = threadIdx.x;
    const int wv = t >> 6, ln = t & 63;
    __shared__ float red[8];

    float v[8];
    float m = -1e30f;
#pragma unroll
    for (int i = 0; i < 8; ++i) {
        v[i] = scoresT[b * SRC_LEN + i * 256 + t];
        m = fmaxf(m, v[i]);
    }
#pragma unroll
    for (int o = 1; o < 64; o <<= 1) m = fmaxf(m, __shfl_xor(m, o));
    if (ln == 0) red[wv] = m;
    __syncthreads();
    m = fmaxf(fmaxf(red[0], red[1]), fmaxf(red[2], red[3]));

    float e[8];
    float ssum = 0.f;
#pragma unroll
    for (int i = 0; i < 8; ++i) {
        e[i] = fast_exp2((v[i] - m) * LOG2E);
        ssum += e[i];
    }
#pragma unroll
    for (int o = 1; o < 64; o <<= 1) ssum += __shfl_xor(ssum, o);
    if (ln == 0) red[4 + wv] = ssum;
    __syncthreads();
    ssum = red[4] + red[5] + red[6] + red[7];

    const float inv = 1.0f / ssum;
#pragma unroll
    for (int i = 0; i < 8; ++i) {
        const float w = e[i] * inv;
        const int sIdx = i * 256 + t;
        wT[b * SRC_LEN + sIdx] = w;
        outNorm[sIdx * BSZ + b] = w;
    }
}

// ---------------------------------------------------------------------------
// Kernel 4: context partial sums. grid (64 b, 16 s-chunks), 128 threads.
// ---------------------------------------------------------------------------
__global__ __launch_bounds__(128) void context_partial(
    const float* __restrict__ hids, const float* __restrict__ wT,
    float* __restrict__ partials)
{
    const int b = blockIdx.x, chunk = blockIdx.y, t = threadIdx.x;
    float4 acc = {0.f, 0.f, 0.f, 0.f};
    const int s0 = chunk * (SRC_LEN / NCHUNK);
#pragma unroll 4
    for (int s = s0; s < s0 + (SRC_LEN / NCHUNK); ++s) {
        const float w = wT[b * SRC_LEN + s];
        if (w != 0.0f) {
            float4 h = reinterpret_cast<const float4*>(hids + (size_t)(s * BSZ + b) * CTX)[t];
            acc.x += w * h.x; acc.y += w * h.y; acc.z += w * h.z; acc.w += w * h.w;
        }
    }
    reinterpret_cast<float4*>(partials + (size_t)(chunk * BSZ + b) * CTX)[t] = acc;
}

// ---------------------------------------------------------------------------
// Kernel 5: reduce partials -> context output. grid 64, 128 threads.
// ---------------------------------------------------------------------------
__global__ __launch_bounds__(128) void context_reduce(
    const float* __restrict__ partials, float* __restrict__ ctx)
{
    const int b = blockIdx.x, t = threadIdx.x;
    float4 acc = {0.f, 0.f, 0.f, 0.f};
#pragma unroll
    for (int c = 0; c < NCHUNK; ++c) {
        float4 p = reinterpret_cast<const float4*>(partials + (size_t)(c * BSZ + b) * CTX)[t];
        acc.x += p.x; acc.y += p.y; acc.z += p.z; acc.w += p.w;
    }
    reinterpret_cast<float4*>(ctx + (size_t)b * CTX)[t] = acc;
}

// ---------------------------------------------------------------------------
extern "C" void kernel_launch(void* const* d_in, const int* in_sizes, int n_in,
                              void* d_out, int out_size, void* d_ws, size_t ws_size,
                              hipStream_t stream)
{
    const float* dec_state = (const float*)d_in[0];
    const float* hids      = (const float*)d_in[1];
    const void*  mask_raw  = d_in[2];
    const float* W_enc     = (const float*)d_in[3];
    const float* b_enc     = (const float*)d_in[4];
    const float* W_dec     = (const float*)d_in[5];
    const float* vvec      = (const float*)d_in[6];

    float* out_ctx  = (float*)d_out;                 // [64][512]
    float* out_norm = out_ctx + BSZ * CTX;           // [2048][64]

    char* ws = (char*)d_ws;
    float* decproj  = (float*)(ws);                  //  64*256*4   = 65536
    u8*    bfrag    = (u8*)(ws + 65536);             // 2 * 262144  = 524288
    float* scoresT  = (float*)(ws + 589824);         // 64*2048*4   = 524288
    float* wT       = (float*)(ws + 1114112);        // 524288
    float* partials = (float*)(ws + 1638400);        // 16*64*512*4 = 2097152
    int*   flag     = (int*)(ws + 3735552);

    hipMemsetAsync(flag, 0, 4, stream);

    prep_kernel<<<64, 256, 0, stream>>>(dec_state, W_dec, W_enc,
                                        (const u8*)mask_raw, decproj, bfrag, flag);

    score_kernel<<<SRC_LEN, 256, 0, stream>>>(
        hids, bfrag, decproj, b_enc, vvec,
        (const u8*)mask_raw, (const int*)mask_raw, flag, scoresT);

    softmax_kernel<<<BSZ, 256, 0, stream>>>(scoresT, wT, out_norm);

    context_partial<<<dim3(BSZ, NCHUNK), 128, 0, stream>>>(hids, wT, partials);

    context_reduce<<<BSZ, 128, 0, stream>>>(partials, out_ctx);
}

// Round 4
// 170.249 us; speedup vs baseline: 1.5576x; 1.5576x over previous
//
#include <hip/hip_runtime.h>
#include <cstdint>

#define SRC_LEN 2048
#define BSZ     64
#define CTX     512
#define ATT     256
#define NT      16          // K tiles = CTX/BK, BK=32
#define NCHUNK  16
#define LOG2E   1.4426950408889634f
#define ABUF    8192        // 64 rows x 32 fp32
#define BBUF    16384       // 256 cols x 32 bf16 (fragment-major)

typedef unsigned short u16;
typedef unsigned int   u32;
typedef unsigned char  u8;
typedef __attribute__((ext_vector_type(8))) short bf16x8;
typedef __attribute__((ext_vector_type(4))) float f32x4;

union U4BF8 { uint4 u; bf16x8 v; };

__device__ __forceinline__ u16 f2bf(float f) {
    u32 u = __float_as_uint(f);
    u32 r = (u + 0x7FFFu + ((u >> 16) & 1u)) >> 16;
    return (u16)r;
}
__device__ __forceinline__ float bf2f(u16 h) { return __uint_as_float((u32)h << 16); }
__device__ __forceinline__ u32 pack2(float a, float b) {
    return (u32)f2bf(a) | ((u32)f2bf(b) << 16);
}

__device__ __forceinline__ float fast_exp2(float x) {
#if __has_builtin(__builtin_amdgcn_exp2f)
    return __builtin_amdgcn_exp2f(x);
#else
    return exp2f(x);
#endif
}
__device__ __forceinline__ float fast_rcp(float x) {
#if __has_builtin(__builtin_amdgcn_rcpf)
    return __builtin_amdgcn_rcpf(x);
#else
    return 1.0f / x;
#endif
}
__device__ __forceinline__ float fast_tanh(float x) {
    float e = fast_exp2(x * (2.0f * LOG2E));
    return 1.0f - 2.0f * fast_rcp(e + 1.0f);
}

// async global->LDS, 16B per lane; LDS dest = wave-uniform base + lane*16,
// global source is PER-LANE (pre-swizzle the source, keep LDS linear).
typedef const __attribute__((address_space(1))) unsigned char ga_u8;
typedef __attribute__((address_space(3))) unsigned char ls_u8;
__device__ __forceinline__ void gl_lds16(const void* g, void* l) {
    __builtin_amdgcn_global_load_lds((ga_u8*)g, (ls_u8*)l, 16, 0, 0);
}

// ---------------------------------------------------------------------------
// Kernel 1: prep — decoder projection; W_enc hi-bf16 written FRAGMENT-MAJOR
// (t, wave, n, lane -> 16B) so score's global_load_lds + ds_read are both
// linear; mask dtype probe. grid 64, 256 threads
// ---------------------------------------------------------------------------
__global__ __launch_bounds__(256) void prep_kernel(
    const float* __restrict__ dec_state, const float* __restrict__ W_dec,
    const float* __restrict__ W_enc, const u8* __restrict__ mask_bytes,
    float* __restrict__ decproj, u8* __restrict__ bfrag,
    int* __restrict__ flag)
{
    const int b = blockIdx.x, t = threadIdx.x;
    __shared__ float ds[CTX];
    for (int k = t; k < CTX; k += 256) ds[k] = dec_state[b * CTX + k];
    __syncthreads();

    // decproj[b][t] = dot(dec_state[b,:], W_dec[t,:])
    const float* wrow = W_dec + t * CTX;
    float acc = 0.f;
#pragma unroll 4
    for (int k = 0; k < CTX; k += 4) {
        float4 w4 = *reinterpret_cast<const float4*>(wrow + k);
        acc += w4.x * ds[k] + w4.y * ds[k + 1] + w4.z * ds[k + 2] + w4.w * ds[k + 3];
    }
    decproj[b * ATT + t] = acc;

    // one thread per (tile, wave, n, lane): 8 consecutive k of one W_enc row
    const int gid  = b * 256 + t;          // 0..16383
    const int lane = gid & 63;
    const int n    = (gid >> 6) & 3;
    const int w    = (gid >> 8) & 3;
    const int tt   = (gid >> 10) & 15;
    const int col  = w * 64 + n * 16 + (lane & 15);   // W_enc row = att col
    const int k0   = tt * 32 + (lane >> 4) * 8;
    const float* src = W_enc + col * CTX + k0;
    float4 f0 = reinterpret_cast<const float4*>(src)[0];
    float4 f1 = reinterpret_cast<const float4*>(src)[1];
    uint4 uh;
    uh.x = pack2(f0.x, f0.y);
    uh.y = pack2(f0.z, f0.w);
    uh.z = pack2(f1.x, f1.y);
    uh.w = pack2(f1.z, f1.w);
    const int dst = tt * BBUF + w * 4096 + n * 1024 + lane * 16;  // bytes
    *reinterpret_cast<uint4*>(bfrag + dst) = uh;

    // mask dtype probe (int32 0/1 has zero bytes at idx%4!=0)
    int bad = 0;
#pragma unroll
    for (int i = 0; i < 8; ++i) {
        int idx = gid * 8 + i;
        if ((idx & 3) != 0 && mask_bytes[idx] != 0) bad = 1;
    }
    if (bad) atomicOr(flag, 1);
}

// ---------------------------------------------------------------------------
// Kernel 2: score — m97-structure 2-phase loop, BOTH operands via
// global_load_lds width-16. A staged as RAW fp32 (XOR-swizzled via per-lane
// source addr, rule #21), converted to bf16 at ds_read time. B pre-split
// hi-bf16, fragment-major, fully linear (conflict-free burst reads).
// Block = one s (64 rows = all b), 4 waves x 64 att-cols. grid 2048.
// ---------------------------------------------------------------------------
__global__ __launch_bounds__(256, 3) void score_kernel(
    const float* __restrict__ hids, const u8* __restrict__ bfrag,
    const float* __restrict__ decproj, const float* __restrict__ b_enc,
    const float* __restrict__ vvec, const u8* __restrict__ maskB,
    const int* __restrict__ maskI, const int* __restrict__ flag,
    float* __restrict__ scoresT)
{
    __shared__ __align__(16) char smem[2 * ABUF + 2 * BBUF];   // 48 KB

    const int tid  = threadIdx.x;
    const int wave = tid >> 6, lane = tid & 63;
    const int ln15 = lane & 15, lg = lane >> 4;
    const int s    = blockIdx.x;

    char* smA = smem;
    char* smB = smem + 2 * ABUF;

    f32x4 acc[4][4];
#pragma unroll
    for (int m = 0; m < 4; ++m)
#pragma unroll
        for (int n = 0; n < 4; ++n) acc[m][n] = (f32x4){0.f, 0.f, 0.f, 0.f};

    // A: 8 KB/step = 8 wave-insts (2/wave). LDS chunk g=(row, c_phys) holds
    // global (row, c_log = c_phys ^ (row&7)) -> read side applies same XOR.
    auto stageA = [&](int t, int buf) {
#pragma unroll
        for (int i = 0; i < 2; ++i) {
            const int g   = (wave * 2 + i) * 64 + lane;   // 16B chunk 0..511
            const int row = g >> 3;
            const int cl  = (g & 7) ^ (row & 7);
            const char* src = (const char*)(hids + (size_t)(s * 64 + row) * CTX + t * 32) + cl * 16;
            char* dst = smA + buf * ABUF + (wave * 2 + i) * 1024;
            gl_lds16(src, dst);
        }
    };
    // B: 16 KB/step = 16 wave-insts (4/wave), fully linear.
    auto stageB = [&](int t, int buf) {
        const char* src = (const char*)bfrag + t * BBUF + wave * 4096 + lane * 16;
        char* dst = smB + buf * BBUF + wave * 4096;
#pragma unroll
        for (int i = 0; i < 4; ++i) gl_lds16(src + i * 1024, dst + i * 1024);
    };

    stageA(0, 0);
    stageB(0, 0);
    __syncthreads();

#pragma unroll 2
    for (int t = 0; t < NT; ++t) {
        const int cur = t & 1;
        if (t < NT - 1) { stageA(t + 1, cur ^ 1); stageB(t + 1, cur ^ 1); }

        // B fragments: linear burst per n
        bf16x8 bf[4];
#pragma unroll
        for (int n = 0; n < 4; ++n) {
            U4BF8 u;
            u.u = *reinterpret_cast<const uint4*>(smB + cur * BBUF + wave * 4096 + n * 1024 + lane * 16);
            bf[n] = u.v;
        }
        // A fragments: swizzled fp32 read + pack to bf16, then 16 MFMA
#pragma unroll
        for (int m = 0; m < 4; ++m) {
            const int r  = m * 16 + ln15;
            const char* ar = smA + cur * ABUF + r * 128;
            const int p0 = (lg * 2) ^ (r & 7);
            const int p1 = (lg * 2 + 1) ^ (r & 7);
            float4 a0 = *reinterpret_cast<const float4*>(ar + p0 * 16);
            float4 a1 = *reinterpret_cast<const float4*>(ar + p1 * 16);
            U4BF8 ua;
            ua.u.x = pack2(a0.x, a0.y);
            ua.u.y = pack2(a0.z, a0.w);
            ua.u.z = pack2(a1.x, a1.y);
            ua.u.w = pack2(a1.z, a1.w);
#pragma unroll
            for (int n = 0; n < 4; ++n)
                acc[m][n] = __builtin_amdgcn_mfma_f32_16x16x32_bf16(ua.v, bf[n], acc[m][n], 0, 0, 0);
        }
        __syncthreads();
    }

    // ---- epilogue: x = enc + b_enc + decproj; partial = sum tanh(x)*v ----
    float* spart = (float*)smem;   // aliases A buf0 (all staging reads done)
    float bE[4], vE[4];
#pragma unroll
    for (int n = 0; n < 4; ++n) {
        const int a = wave * 64 + n * 16 + ln15;
        bE[n] = b_enc[a];
        vE[n] = vvec[a];
    }
    const float* dpb = decproj + wave * 64 + ln15;
#pragma unroll
    for (int m = 0; m < 4; ++m) {
#pragma unroll
        for (int j = 0; j < 4; ++j) {
            const int rl = m * 16 + lg * 4 + j;     // = b index
            float partial = 0.f;
#pragma unroll
            for (int n = 0; n < 4; ++n) {
                float x = acc[m][n][j] + bE[n] + dpb[rl * ATT + n * 16];
                partial += fast_tanh(x) * vE[n];
            }
            partial += __shfl_xor(partial, 1);
            partial += __shfl_xor(partial, 2);
            partial += __shfl_xor(partial, 4);
            partial += __shfl_xor(partial, 8);
            if (ln15 == 0) spart[wave * 64 + rl] = partial;
        }
    }
    __syncthreads();

    if (tid < 64) {
        const int b = tid;
        float sc = spart[0 * 64 + b] + spart[1 * 64 + b] +
                   spart[2 * 64 + b] + spart[3 * 64 + b];
        const int isByte = *flag;
        int mv;
        if (isByte) mv = (int)maskB[s * BSZ + b];
        else        mv = maskI[s * BSZ + b];
        scoresT[b * SRC_LEN + s] = (mv != 0) ? -1e30f : sc;
    }
}

// ---------------------------------------------------------------------------
// Kernel 3: softmax over s per batch column b. grid 64, 256 threads.
// ---------------------------------------------------------------------------
__global__ __launch_bounds__(256) void softmax_kernel(
    const float* __restrict__ scoresT, float* __restrict__ wT,
    float* __restrict__ outNorm)
{
    const int b = blockIdx.x, t = threadIdx.x;
    const int wv = t >> 6, ln = t & 63;
    __shared__ float red[8];

    float v[8];
    float m = -1e30f;
#pragma unroll
    for (int i = 0; i < 8; ++i) {
        v[i] = scoresT[b * SRC_LEN + i * 256 + t];
        m = fmaxf(m, v[i]);
    }
#pragma unroll
    for (int o = 1; o < 64; o <<= 1) m = fmaxf(m, __shfl_xor(m, o));
    if (ln == 0) red[wv] = m;
    __syncthreads();
    m = fmaxf(fmaxf(red[0], red[1]), fmaxf(red[2], red[3]));

    float e[8];
    float ssum = 0.f;
#pragma unroll
    for (int i = 0; i < 8; ++i) {
        e[i] = fast_exp2((v[i] - m) * LOG2E);
        ssum += e[i];
    }
#pragma unroll
    for (int o = 1; o < 64; o <<= 1) ssum += __shfl_xor(ssum, o);
    if (ln == 0) red[4 + wv] = ssum;
    __syncthreads();
    ssum = red[4] + red[5] + red[6] + red[7];

    const float inv = 1.0f / ssum;
#pragma unroll
    for (int i = 0; i < 8; ++i) {
        const float w = e[i] * inv;
        const int sIdx = i * 256 + t;
        wT[b * SRC_LEN + sIdx] = w;
        outNorm[sIdx * BSZ + b] = w;
    }
}

// ---------------------------------------------------------------------------
// Kernel 4: context partial sums. grid (64 b, 16 s-chunks), 128 threads.
// ---------------------------------------------------------------------------
__global__ __launch_bounds__(128) void context_partial(
    const float* __restrict__ hids, const float* __restrict__ wT,
    float* __restrict__ partials)
{
    const int b = blockIdx.x, chunk = blockIdx.y, t = threadIdx.x;
    float4 acc = {0.f, 0.f, 0.f, 0.f};
    const int s0 = chunk * (SRC_LEN / NCHUNK);
#pragma unroll 4
    for (int s = s0; s < s0 + (SRC_LEN / NCHUNK); ++s) {
        const float w = wT[b * SRC_LEN + s];
        if (w != 0.0f) {
            float4 h = reinterpret_cast<const float4*>(hids + (size_t)(s * BSZ + b) * CTX)[t];
            acc.x += w * h.x; acc.y += w * h.y; acc.z += w * h.z; acc.w += w * h.w;
        }
    }
    reinterpret_cast<float4*>(partials + (size_t)(chunk * BSZ + b) * CTX)[t] = acc;
}

// ---------------------------------------------------------------------------
// Kernel 5: reduce partials -> context output. grid 64, 128 threads.
// ---------------------------------------------------------------------------
__global__ __launch_bounds__(128) void context_reduce(
    const float* __restrict__ partials, float* __restrict__ ctx)
{
    const int b = blockIdx.x, t = threadIdx.x;
    float4 acc = {0.f, 0.f, 0.f, 0.f};
#pragma unroll
    for (int c = 0; c < NCHUNK; ++c) {
        float4 p = reinterpret_cast<const float4*>(partials + (size_t)(c * BSZ + b) * CTX)[t];
        acc.x += p.x; acc.y += p.y; acc.z += p.z; acc.w += p.w;
    }
    reinterpret_cast<float4*>(ctx + (size_t)b * CTX)[t] = acc;
}

// ---------------------------------------------------------------------------
extern "C" void kernel_launch(void* const* d_in, const int* in_sizes, int n_in,
                              void* d_out, int out_size, void* d_ws, size_t ws_size,
                              hipStream_t stream)
{
    const float* dec_state = (const float*)d_in[0];
    const float* hids      = (const float*)d_in[1];
    const void*  mask_raw  = d_in[2];
    const float* W_enc     = (const float*)d_in[3];
    const float* b_enc     = (const float*)d_in[4];
    const float* W_dec     = (const float*)d_in[5];
    const float* vvec      = (const float*)d_in[6];

    float* out_ctx  = (float*)d_out;                 // [64][512]
    float* out_norm = out_ctx + BSZ * CTX;           // [2048][64]

    char* ws = (char*)d_ws;
    float* decproj  = (float*)(ws);                  //  64*256*4   = 65536
    u8*    bfrag    = (u8*)(ws + 65536);             // 16*16384    = 262144
    float* scoresT  = (float*)(ws + 589824);         // 64*2048*4   = 524288
    float* wT       = (float*)(ws + 1114112);        // 524288
    float* partials = (float*)(ws + 1638400);        // 16*64*512*4 = 2097152
    int*   flag     = (int*)(ws + 3735552);

    hipMemsetAsync(flag, 0, 4, stream);

    prep_kernel<<<64, 256, 0, stream>>>(dec_state, W_dec, W_enc,
                                        (const u8*)mask_raw, decproj, bfrag, flag);

    score_kernel<<<SRC_LEN, 256, 0, stream>>>(
        hids, bfrag, decproj, b_enc, vvec,
        (const u8*)mask_raw, (const int*)mask_raw, flag, scoresT);

    softmax_kernel<<<BSZ, 256, 0, stream>>>(scoresT, wT, out_norm);

    context_partial<<<dim3(BSZ, NCHUNK), 128, 0, stream>>>(hids, wT, partials);

    context_reduce<<<BSZ, 128, 0, stream>>>(partials, out_ctx);
}

// Round 5
// 165.512 us; speedup vs baseline: 1.6021x; 1.0286x over previous
//
#include <hip/hip_runtime.h>
#include <cstdint>

#define SRC_LEN 2048
#define BSZ     64
#define CTX     512
#define ATT     256
#define NT      16          // K tiles = CTX/BK, BK=32
#define NCHUNK  16
#define LOG2E   1.4426950408889634f
#define ABUF    8192        // 64 rows x 32 fp32 per A tile
#define BBUF    16384       // 256 cols x 32 bf16 per B tile (fragment-major)

typedef unsigned short u16;
typedef unsigned int   u32;
typedef unsigned char  u8;
typedef __attribute__((ext_vector_type(8))) short bf16x8;
typedef __attribute__((ext_vector_type(4))) float f32x4;

union U4BF8 { uint4 u; bf16x8 v; };

__device__ __forceinline__ u16 f2bf(float f) {
    u32 u = __float_as_uint(f);
    u32 r = (u + 0x7FFFu + ((u >> 16) & 1u)) >> 16;
    return (u16)r;
}
__device__ __forceinline__ float bf2f(u16 h) { return __uint_as_float((u32)h << 16); }
__device__ __forceinline__ u32 pack2(float a, float b) {
    return (u32)f2bf(a) | ((u32)f2bf(b) << 16);
}

__device__ __forceinline__ float fast_exp2(float x) {
#if __has_builtin(__builtin_amdgcn_exp2f)
    return __builtin_amdgcn_exp2f(x);
#else
    return exp2f(x);
#endif
}
__device__ __forceinline__ float fast_rcp(float x) {
#if __has_builtin(__builtin_amdgcn_rcpf)
    return __builtin_amdgcn_rcpf(x);
#else
    return 1.0f / x;
#endif
}
__device__ __forceinline__ float fast_tanh(float x) {
    float e = fast_exp2(x * (2.0f * LOG2E));
    return 1.0f - 2.0f * fast_rcp(e + 1.0f);
}

// async global->LDS, 16B per lane; LDS dest = wave-uniform base + lane*16,
// global source is PER-LANE (pre-swizzle the source, keep LDS linear).
typedef const __attribute__((address_space(1))) unsigned char ga_u8;
typedef __attribute__((address_space(3))) unsigned char ls_u8;
__device__ __forceinline__ void gl_lds16(const void* g, void* l) {
    __builtin_amdgcn_global_load_lds((ga_u8*)g, (ls_u8*)l, 16, 0, 0);
}

// ---------------------------------------------------------------------------
// Kernel 1: prep — decoder projection; W_enc hi-bf16 written FRAGMENT-MAJOR
// (t, wave, n, lane -> 16B) so score's B loads are single coalesced dwordx4;
// mask dtype probe. grid 64, 256 threads
// ---------------------------------------------------------------------------
__global__ __launch_bounds__(256) void prep_kernel(
    const float* __restrict__ dec_state, const float* __restrict__ W_dec,
    const float* __restrict__ W_enc, const u8* __restrict__ mask_bytes,
    float* __restrict__ decproj, u8* __restrict__ bfrag,
    int* __restrict__ flag)
{
    const int b = blockIdx.x, t = threadIdx.x;
    __shared__ float ds[CTX];
    for (int k = t; k < CTX; k += 256) ds[k] = dec_state[b * CTX + k];
    __syncthreads();

    // decproj[b][t] = dot(dec_state[b,:], W_dec[t,:])
    const float* wrow = W_dec + t * CTX;
    float acc = 0.f;
#pragma unroll 4
    for (int k = 0; k < CTX; k += 4) {
        float4 w4 = *reinterpret_cast<const float4*>(wrow + k);
        acc += w4.x * ds[k] + w4.y * ds[k + 1] + w4.z * ds[k + 2] + w4.w * ds[k + 3];
    }
    decproj[b * ATT + t] = acc;

    // one thread per (tile, wave, n, lane): 8 consecutive k of one W_enc row
    const int gid  = b * 256 + t;          // 0..16383
    const int lane = gid & 63;
    const int n    = (gid >> 6) & 3;
    const int w    = (gid >> 8) & 3;
    const int tt   = (gid >> 10) & 15;
    const int col  = w * 64 + n * 16 + (lane & 15);   // W_enc row = att col
    const int k0   = tt * 32 + (lane >> 4) * 8;
    const float* src = W_enc + col * CTX + k0;
    float4 f0 = reinterpret_cast<const float4*>(src)[0];
    float4 f1 = reinterpret_cast<const float4*>(src)[1];
    uint4 uh;
    uh.x = pack2(f0.x, f0.y);
    uh.y = pack2(f0.z, f0.w);
    uh.z = pack2(f1.x, f1.y);
    uh.w = pack2(f1.z, f1.w);
    const int dst = tt * BBUF + w * 4096 + n * 1024 + lane * 16;  // bytes
    *reinterpret_cast<uint4*>(bfrag + dst) = uh;

    // mask dtype probe (int32 0/1 has zero bytes at idx%4!=0)
    int bad = 0;
#pragma unroll
    for (int i = 0; i < 8; ++i) {
        int idx = gid * 8 + i;
        if ((idx & 3) != 0 && mask_bytes[idx] != 0) bad = 1;
    }
    if (bad) atomicOr(flag, 1);
}

// ---------------------------------------------------------------------------
// Kernel 2: score — counted-vmcnt pipeline (T3/T4):
//   A: fp32 via global_load_lds, TRIPLE-buffered LDS, staged 2 steps ahead,
//      XOR-swizzled via per-lane source addr (rule #21).
//   B: hi-bf16 fragment-major, inline-asm global_load_dwordx4 into registers,
//      double-buffered, loaded 1 step ahead (L2-hot).
//   One raw s_barrier/step + s_waitcnt vmcnt(2) (never 0 in-loop);
//   sched_barrier(0) pins compute below the wait (rule #18).
// Queue entering step t (old->new): A(t)x2, B(t)x4, A(t+1)x2 -> vmcnt(2).
// Block = one s (64 rows = all b), 4 waves x 64 att-cols. grid 2048.
// ---------------------------------------------------------------------------
__global__ __launch_bounds__(256, 3) void score_kernel(
    const float* __restrict__ hids, const u8* __restrict__ bfrag,
    const float* __restrict__ decproj, const float* __restrict__ b_enc,
    const float* __restrict__ vvec, const u8* __restrict__ maskB,
    const int* __restrict__ maskI, const int* __restrict__ flag,
    float* __restrict__ scoresT)
{
    __shared__ __align__(16) char smA[3 * ABUF];   // 24 KB
    __shared__ float spart[4][64];

    const int tid  = threadIdx.x;
    const int wave = tid >> 6, lane = tid & 63;
    const int ln15 = lane & 15, lg = lane >> 4;
    const int s    = blockIdx.x;

    f32x4 acc[4][4];
#pragma unroll
    for (int m = 0; m < 4; ++m)
#pragma unroll
        for (int n = 0; n < 4; ++n) acc[m][n] = (f32x4){0.f, 0.f, 0.f, 0.f};

    // A stage: 8 KB/step = 2 gl_lds insts/wave; swizzle on the SOURCE side.
    auto stageA = [&](int t, int buf) {
#pragma unroll
        for (int i = 0; i < 2; ++i) {
            const int g   = (wave * 2 + i) * 64 + lane;   // 16B chunk 0..511
            const int row = g >> 3;
            const int cl  = (g & 7) ^ (row & 7);
            const char* src = (const char*)(hids + (size_t)(s * 64 + row) * CTX + t * 32) + cl * 16;
            gl_lds16(src, smA + buf * ABUF + (wave * 2 + i) * 1024);
        }
    };

    const u8* bptr = bfrag;
    const u32 wb = wave * 4096 + lane * 16;
    uint4 bq[2][4];

#define LOADB(t, slot) do {                                                             \
    const u32 voff = wb + (u32)(t) * BBUF;                                              \
    asm volatile("global_load_dwordx4 %0, %1, %2 offset:0"                              \
                 : "=v"(bq[slot][0]) : "v"(voff), "s"(bptr) : "memory");                \
    asm volatile("global_load_dwordx4 %0, %1, %2 offset:1024"                           \
                 : "=v"(bq[slot][1]) : "v"(voff), "s"(bptr) : "memory");                \
    asm volatile("global_load_dwordx4 %0, %1, %2 offset:2048"                           \
                 : "=v"(bq[slot][2]) : "v"(voff), "s"(bptr) : "memory");                \
    asm volatile("global_load_dwordx4 %0, %1, %2 offset:3072"                           \
                 : "=v"(bq[slot][3]) : "v"(voff), "s"(bptr) : "memory");                \
} while (0)

    // prologue: queue (old->new) = A(0)x2, B(0)x4, A(1)x2
    stageA(0, 0);
    LOADB(0, 0);
    stageA(1, 1);

#pragma unroll
    for (int t = 0; t < NT; ++t) {
        if (t < NT - 1) asm volatile("s_waitcnt vmcnt(2)" ::: "memory");
        else            asm volatile("s_waitcnt vmcnt(0)" ::: "memory");
        __builtin_amdgcn_s_barrier();
        __builtin_amdgcn_sched_barrier(0);

        // issue next-step vmem FIRST (B before A keeps the queue pattern)
        if (t + 1 < NT) LOADB(t + 1, (t + 1) & 1);
        if (t + 2 < NT) stageA(t + 2, (t + 2) % 3);

        const char* ab = smA + (t % 3) * ABUF;
        bf16x8 bf[4];
#pragma unroll
        for (int n = 0; n < 4; ++n) {
            U4BF8 u; u.u = bq[t & 1][n]; bf[n] = u.v;
        }
#pragma unroll
        for (int m = 0; m < 4; ++m) {
            const int r  = m * 16 + ln15;
            const char* ar = ab + r * 128;
            const int p0 = (lg * 2) ^ (r & 7);
            const int p1 = (lg * 2 + 1) ^ (r & 7);
            float4 a0 = *reinterpret_cast<const float4*>(ar + p0 * 16);
            float4 a1 = *reinterpret_cast<const float4*>(ar + p1 * 16);
            U4BF8 ua;
            ua.u.x = pack2(a0.x, a0.y);
            ua.u.y = pack2(a0.z, a0.w);
            ua.u.z = pack2(a1.x, a1.y);
            ua.u.w = pack2(a1.z, a1.w);
#pragma unroll
            for (int n = 0; n < 4; ++n)
                acc[m][n] = __builtin_amdgcn_mfma_f32_16x16x32_bf16(ua.v, bf[n], acc[m][n], 0, 0, 0);
        }
    }
#undef LOADB

    // ---- epilogue: x = enc + b_enc + decproj; partial = sum tanh(x)*v ----
    float bE[4], vE[4];
#pragma unroll
    for (int n = 0; n < 4; ++n) {
        const int a = wave * 64 + n * 16 + ln15;
        bE[n] = b_enc[a];
        vE[n] = vvec[a];
    }
    const float* dpb = decproj + wave * 64 + ln15;
#pragma unroll
    for (int m = 0; m < 4; ++m) {
#pragma unroll
        for (int j = 0; j < 4; ++j) {
            const int rl = m * 16 + lg * 4 + j;     // = b index
            float partial = 0.f;
#pragma unroll
            for (int n = 0; n < 4; ++n) {
                float x = acc[m][n][j] + bE[n] + dpb[rl * ATT + n * 16];
                partial += fast_tanh(x) * vE[n];
            }
            partial += __shfl_xor(partial, 1);
            partial += __shfl_xor(partial, 2);
            partial += __shfl_xor(partial, 4);
            partial += __shfl_xor(partial, 8);
            if (ln15 == 0) spart[wave][rl] = partial;
        }
    }
    __syncthreads();

    if (tid < 64) {
        const int b = tid;
        float sc = spart[0][b] + spart[1][b] + spart[2][b] + spart[3][b];
        const int isByte = *flag;
        int mv;
        if (isByte) mv = (int)maskB[s * BSZ + b];
        else        mv = maskI[s * BSZ + b];
        scoresT[b * SRC_LEN + s] = (mv != 0) ? -1e30f : sc;
    }
}

// ---------------------------------------------------------------------------
// Kernel 3: softmax over s per batch column b. grid 64, 256 threads.
// ---------------------------------------------------------------------------
__global__ __launch_bounds__(256) void softmax_kernel(
    const float* __restrict__ scoresT, float* __restrict__ wT,
    float* __restrict__ outNorm)
{
    const int b = blockIdx.x, t = threadIdx.x;
    const int wv = t >> 6, ln = t & 63;
    __shared__ float red[8];

    float v[8];
    float m = -1e30f;
#pragma unroll
    for (int i = 0; i < 8; ++i) {
        v[i] = scoresT[b * SRC_LEN + i * 256 + t];
        m = fmaxf(m, v[i]);
    }
#pragma unroll
    for (int o = 1; o < 64; o <<= 1) m = fmaxf(m, __shfl_xor(m, o));
    if (ln == 0) red[wv] = m;
    __syncthreads();
    m = fmaxf(fmaxf(red[0], red[1]), fmaxf(red[2], red[3]));

    float e[8];
    float ssum = 0.f;
#pragma unroll
    for (int i = 0; i < 8; ++i) {
        e[i] = fast_exp2((v[i] - m) * LOG2E);
        ssum += e[i];
    }
#pragma unroll
    for (int o = 1; o < 64; o <<= 1) ssum += __shfl_xor(ssum, o);
    if (ln == 0) red[4 + wv] = ssum;
    __syncthreads();
    ssum = red[4] + red[5] + red[6] + red[7];

    const float inv = 1.0f / ssum;
#pragma unroll
    for (int i = 0; i < 8; ++i) {
        const float w = e[i] * inv;
        const int sIdx = i * 256 + t;
        wT[b * SRC_LEN + sIdx] = w;
        outNorm[sIdx * BSZ + b] = w;
    }
}

// ---------------------------------------------------------------------------
// Kernel 4: context partial sums. grid (64 b, 16 s-chunks), 128 threads.
// ---------------------------------------------------------------------------
__global__ __launch_bounds__(128) void context_partial(
    const float* __restrict__ hids, const float* __restrict__ wT,
    float* __restrict__ partials)
{
    const int b = blockIdx.x, chunk = blockIdx.y, t = threadIdx.x;
    float4 acc = {0.f, 0.f, 0.f, 0.f};
    const int s0 = chunk * (SRC_LEN / NCHUNK);
#pragma unroll 4
    for (int s = s0; s < s0 + (SRC_LEN / NCHUNK); ++s) {
        const float w = wT[b * SRC_LEN + s];
        if (w != 0.0f) {
            float4 h = reinterpret_cast<const float4*>(hids + (size_t)(s * BSZ + b) * CTX)[t];
            acc.x += w * h.x; acc.y += w * h.y; acc.z += w * h.z; acc.w += w * h.w;
        }
    }
    reinterpret_cast<float4*>(partials + (size_t)(chunk * BSZ + b) * CTX)[t] = acc;
}

// ---------------------------------------------------------------------------
// Kernel 5: reduce partials -> context output. grid 64, 128 threads.
// ---------------------------------------------------------------------------
__global__ __launch_bounds__(128) void context_reduce(
    const float* __restrict__ partials, float* __restrict__ ctx)
{
    const int b = blockIdx.x, t = threadIdx.x;
    float4 acc = {0.f, 0.f, 0.f, 0.f};
#pragma unroll
    for (int c = 0; c < NCHUNK; ++c) {
        float4 p = reinterpret_cast<const float4*>(partials + (size_t)(c * BSZ + b) * CTX)[t];
        acc.x += p.x; acc.y += p.y; acc.z += p.z; acc.w += p.w;
    }
    reinterpret_cast<float4*>(ctx + (size_t)b * CTX)[t] = acc;
}

// ---------------------------------------------------------------------------
extern "C" void kernel_launch(void* const* d_in, const int* in_sizes, int n_in,
                              void* d_out, int out_size, void* d_ws, size_t ws_size,
                              hipStream_t stream)
{
    const float* dec_state = (const float*)d_in[0];
    const float* hids      = (const float*)d_in[1];
    const void*  mask_raw  = d_in[2];
    const float* W_enc     = (const float*)d_in[3];
    const float* b_enc     = (const float*)d_in[4];
    const float* W_dec     = (const float*)d_in[5];
    const float* vvec      = (const float*)d_in[6];

    float* out_ctx  = (float*)d_out;                 // [64][512]
    float* out_norm = out_ctx + BSZ * CTX;           // [2048][64]

    char* ws = (char*)d_ws;
    float* decproj  = (float*)(ws);                  //  64*256*4   = 65536
    u8*    bfrag    = (u8*)(ws + 65536);             // 16*16384    = 262144
    float* scoresT  = (float*)(ws + 589824);         // 64*2048*4   = 524288
    float* wT       = (float*)(ws + 1114112);        // 524288
    float* partials = (float*)(ws + 1638400);        // 16*64*512*4 = 2097152
    int*   flag     = (int*)(ws + 3735552);

    hipMemsetAsync(flag, 0, 4, stream);

    prep_kernel<<<64, 256, 0, stream>>>(dec_state, W_dec, W_enc,
                                        (const u8*)mask_raw, decproj, bfrag, flag);

    score_kernel<<<SRC_LEN, 256, 0, stream>>>(
        hids, bfrag, decproj, b_enc, vvec,
        (const u8*)mask_raw, (const int*)mask_raw, flag, scoresT);

    softmax_kernel<<<BSZ, 256, 0, stream>>>(scoresT, wT, out_norm);

    context_partial<<<dim3(BSZ, NCHUNK), 128, 0, stream>>>(hids, wT, partials);

    context_reduce<<<BSZ, 128, 0, stream>>>(partials, out_ctx);
}